// Round 4
// baseline (614.718 us; speedup 1.0000x reference)
//
#include <hip/hip_runtime.h>
#include <hip/hip_fp16.h>
#include <math.h>

// Longformer global attention, fixed shapes: B=2,H=12,S=2048,D=64,N_GLOBAL=128.
// Output 0: context (B,H,S,D) fp32 ; Output 1: probs (B,H,S,S) fp32 (cols>=128 zero).
// Two block roles in one kernel (Z-role fused into A):
//   [0,NB)     B: full 2048-key online-softmax attention for q<128 rows -> ctx
//   [NB,NB+NA) A: 128-key softmax for its 16 rows -> probs cols 0..127,
//                 zero-fill of probs cols 128..2047 for the SAME rows,
//                 and ctx = P @ V[0:128] for non-global rows (qbase>=128).
// LDS = 34816 (k, pitch 68 -> conflict-free b128) + 4096 (P as fp16) = 38912 B
//     -> 4 blocks/CU (16 waves) instead of 3.

namespace {
constexpr int BATCH = 2;
constexpr int HEADS = 12;
constexpr int SEQ   = 2048;
constexpr int DIM   = 64;
constexpr int NG    = 128;
constexpr int BHN   = BATCH * HEADS;                        // 24
constexpr long long CTX_SIZE = (long long)BHN * SEQ * DIM;  // 3,145,728
constexpr float SCALE = 0.125f;                             // 1/sqrt(64)

constexpr int NB_BLOCKS = (BHN * NG) / 16;                  // 192
constexpr int NA_BLOCKS = (BHN * SEQ) / 16;                 // 3072
constexpr int TAIL_F4   = (SEQ - NG) / 4;                   // 480 float4 per row tail
constexpr int TAIL_PER_THREAD = 16 * TAIL_F4 / 256;         // 30 float4 per thread
}

typedef float nfloat4 __attribute__((ext_vector_type(4)));

__device__ __forceinline__ float wave_max64(float x) {
#pragma unroll
    for (int off = 32; off > 0; off >>= 1) x = fmaxf(x, __shfl_xor(x, off));
    return x;
}
__device__ __forceinline__ float wave_sum64(float x) {
#pragma unroll
    for (int off = 32; off > 0; off >>= 1) x += __shfl_xor(x, off);
    return x;
}

__global__ __launch_bounds__(256) void longformer_fused(
    const float* __restrict__ q, const float* __restrict__ k,
    const float* __restrict__ v, float* __restrict__ out)
{
    __shared__ float  k_lds[128][68];    // 34816 B, pitch 17 f4 -> conflict-free b128 reads
    __shared__ __half p_lds[4][4][128];  //  4096 B

    const int blk = blockIdx.x;
    float* const ctx_out   = out;
    float* const probs_out = out + CTX_SIZE;

    const int w    = threadIdx.x >> 6;
    const int lane = threadIdx.x & 63;
    const int gq   = lane >> 4;   // 0..3
    const int dq   = lane & 15;   // 0..15

    if (blk >= NB_BLOCKS) {
        // ---- A: 128-key global softmax + own-row tail zeroing ----
        const int ablk  = blk - NB_BLOCKS;
        const int bh    = ablk >> 7;          // 128 blocks per (b,h)
        const int qbase = (ablk & 127) << 4;  // 16 rows per block
        const int row0  = qbase + w * 4;
        const float* const qb = q + (size_t)bh * SEQ * DIM;
        const float* const kb = k + (size_t)bh * SEQ * DIM;   // global keys = rows 0..127
        const float* const vb = v + (size_t)bh * SEQ * DIM;

        // stage k[0:128][0:64] -> LDS (coalesced), loads issued first
#pragma unroll
        for (int j = 0; j < 8; ++j) {
            int f  = threadIdx.x + j * 256;       // float4 index 0..2047
            int g  = f >> 4;
            int ci = (f & 15) << 2;
            float4 t = *reinterpret_cast<const float4*>(kb + g * DIM + ci);
            *reinterpret_cast<float4*>(&k_lds[g][ci]) = t;
        }

        // zero-fill probs[rows qbase..qbase+15][128:2048], nontemporal, drains under compute
        {
            float* const tail_base = probs_out + ((size_t)bh * SEQ + qbase) * SEQ;
            const nfloat4 z = (nfloat4)(0.f);
#pragma unroll
            for (int s = 0; s < TAIL_PER_THREAD; ++s) {
                int idx  = s * 256 + threadIdx.x;       // 0..7679
                int row  = idx / TAIL_F4;               // 0..15
                int c4   = idx - row * TAIL_F4;         // 0..479
                nfloat4* p = reinterpret_cast<nfloat4*>(tail_base + (size_t)row * SEQ + NG + 4 * c4);
                __builtin_nontemporal_store(z, p);
            }
        }
        __syncthreads();

        // scores: lane owns keys g=lane and g=lane+64
        float s0[4] = {0,0,0,0}, s1[4] = {0,0,0,0};
        const float* krow0 = &k_lds[lane][0];
        const float* krow1 = &k_lds[lane + 64][0];
#pragma unroll 4
        for (int i = 0; i < 16; ++i) {
            const float4 ka = *reinterpret_cast<const float4*>(krow0 + 4 * i);
            const float4 kc = *reinterpret_cast<const float4*>(krow1 + 4 * i);
#pragma unroll
            for (int r = 0; r < 4; ++r) {
                const float4 qv = *reinterpret_cast<const float4*>(qb + (size_t)(row0 + r) * DIM + 4 * i);
                s0[r] += qv.x * ka.x + qv.y * ka.y + qv.z * ka.z + qv.w * ka.w;
                s1[r] += qv.x * kc.x + qv.y * kc.y + qv.z * kc.z + qv.w * kc.w;
            }
        }
#pragma unroll
        for (int r = 0; r < 4; ++r) {
            float a = s0[r] * SCALE, b = s1[r] * SCALE;
            float m = wave_max64(fmaxf(a, b));
            float e0 = __expf(a - m), e1 = __expf(b - m);
            float inv = 1.f / wave_sum64(e0 + e1);
            e0 *= inv; e1 *= inv;
            p_lds[w][r][lane]      = __float2half(e0);
            p_lds[w][r][lane + 64] = __float2half(e1);
            float* prow = probs_out + (size_t)(bh * SEQ + row0 + r) * SEQ;
            __builtin_nontemporal_store(e0, prow + lane);
            __builtin_nontemporal_store(e1, prow + lane + 64);
        }
        __syncthreads();

        if (qbase >= NG) {  // uniform per block: non-global rows need ctx = P @ V[0:128]
            float4 c[4];
#pragma unroll
            for (int r = 0; r < 4; ++r) c[r] = make_float4(0.f, 0.f, 0.f, 0.f);
#pragma unroll 2
            for (int i = 0; i < 32; ++i) {
                const int g = 4 * i + gq;
                const float4 vv = *reinterpret_cast<const float4*>(vb + g * DIM + 4 * dq);
#pragma unroll
                for (int r = 0; r < 4; ++r) {
                    const float pr = __half2float(p_lds[w][r][g]);
                    c[r].x += pr * vv.x; c[r].y += pr * vv.y;
                    c[r].z += pr * vv.z; c[r].w += pr * vv.w;
                }
            }
#pragma unroll
            for (int r = 0; r < 4; ++r) {
                c[r].x += __shfl_xor(c[r].x, 16); c[r].y += __shfl_xor(c[r].y, 16);
                c[r].z += __shfl_xor(c[r].z, 16); c[r].w += __shfl_xor(c[r].w, 16);
                c[r].x += __shfl_xor(c[r].x, 32); c[r].y += __shfl_xor(c[r].y, 32);
                c[r].z += __shfl_xor(c[r].z, 32); c[r].w += __shfl_xor(c[r].w, 32);
                if (lane < 16) {
                    nfloat4 cv; cv.x = c[r].x; cv.y = c[r].y; cv.z = c[r].z; cv.w = c[r].w;
                    nfloat4* crow = reinterpret_cast<nfloat4*>(ctx_out + (size_t)(bh * SEQ + row0 + r) * DIM + 4 * dq);
                    __builtin_nontemporal_store(cv, crow);
                }
            }
        }
        return;
    }

    // ---- B: full 2048-key attention for global queries (q<128) ----
    {
        const int bh    = blk >> 3;          // 8 blocks per (b,h)
        const int qbase = (blk & 7) << 4;
        const int row0  = qbase + w * 4;
        const float* const qb = q + (size_t)bh * SEQ * DIM;
        const float* const kb = k + (size_t)bh * SEQ * DIM;
        const float* const vb = v + (size_t)bh * SEQ * DIM;

        float m[4], l[4];
        float4 c[4];
#pragma unroll
        for (int r = 0; r < 4; ++r) { m[r] = -INFINITY; l[r] = 0.f; c[r] = make_float4(0.f,0.f,0.f,0.f); }

        for (int t = 0; t < 16; ++t) {
            const float* kt = kb + (size_t)t * 128 * DIM;
            const float* vt = vb + (size_t)t * 128 * DIM;

            __syncthreads();  // protect k_lds from previous tile's readers
#pragma unroll
            for (int j = 0; j < 8; ++j) {
                int f  = threadIdx.x + j * 256;
                int g  = f >> 4;
                int ci = (f & 15) << 2;
                float4 tt = *reinterpret_cast<const float4*>(kt + g * DIM + ci);
                *reinterpret_cast<float4*>(&k_lds[g][ci]) = tt;
            }
            __syncthreads();

            float s0[4] = {0,0,0,0}, s1[4] = {0,0,0,0};
            const float* krow0 = &k_lds[lane][0];
            const float* krow1 = &k_lds[lane + 64][0];
#pragma unroll 4
            for (int i = 0; i < 16; ++i) {
                const float4 ka = *reinterpret_cast<const float4*>(krow0 + 4 * i);
                const float4 kc = *reinterpret_cast<const float4*>(krow1 + 4 * i);
#pragma unroll
                for (int r = 0; r < 4; ++r) {
                    const float4 qv = *reinterpret_cast<const float4*>(qb + (size_t)(row0 + r) * DIM + 4 * i);
                    s0[r] += qv.x * ka.x + qv.y * ka.y + qv.z * ka.z + qv.w * ka.w;
                    s1[r] += qv.x * kc.x + qv.y * kc.y + qv.z * kc.z + qv.w * kc.w;
                }
            }
#pragma unroll
            for (int r = 0; r < 4; ++r) {
                float a  = s0[r] * SCALE, b = s1[r] * SCALE;
                float tm = wave_max64(fmaxf(a, b));
                float mn = fmaxf(m[r], tm);
                float corr = __expf(m[r] - mn);       // exp(-inf)=0 on first tile
                float e0 = __expf(a - mn), e1 = __expf(b - mn);
                float ts = wave_sum64(e0 + e1);
                l[r] = l[r] * corr + ts;
                c[r].x *= corr; c[r].y *= corr; c[r].z *= corr; c[r].w *= corr;
                m[r] = mn;
                p_lds[w][r][lane]      = __float2half(e0);
                p_lds[w][r][lane + 64] = __float2half(e1);
            }
            __syncthreads();
#pragma unroll 2
            for (int i = 0; i < 32; ++i) {
                const int g = 4 * i + gq;
                const float4 vv = *reinterpret_cast<const float4*>(vt + g * DIM + 4 * dq);
#pragma unroll
                for (int r = 0; r < 4; ++r) {
                    const float pr = __half2float(p_lds[w][r][g]);
                    c[r].x += pr * vv.x; c[r].y += pr * vv.y;
                    c[r].z += pr * vv.z; c[r].w += pr * vv.w;
                }
            }
        }
#pragma unroll
        for (int r = 0; r < 4; ++r) {
            c[r].x += __shfl_xor(c[r].x, 16); c[r].y += __shfl_xor(c[r].y, 16);
            c[r].z += __shfl_xor(c[r].z, 16); c[r].w += __shfl_xor(c[r].w, 16);
            c[r].x += __shfl_xor(c[r].x, 32); c[r].y += __shfl_xor(c[r].y, 32);
            c[r].z += __shfl_xor(c[r].z, 32); c[r].w += __shfl_xor(c[r].w, 32);
            const float inv = 1.f / l[r];
            c[r].x *= inv; c[r].y *= inv; c[r].z *= inv; c[r].w *= inv;
            if (lane < 16) {
                nfloat4 cv; cv.x = c[r].x; cv.y = c[r].y; cv.z = c[r].z; cv.w = c[r].w;
                nfloat4* crow = reinterpret_cast<nfloat4*>(ctx_out + (size_t)(bh * SEQ + row0 + r) * DIM + 4 * dq);
                __builtin_nontemporal_store(cv, crow);
            }
        }
    }
}

extern "C" void kernel_launch(void* const* d_in, const int* in_sizes, int n_in,
                              void* d_out, int out_size, void* d_ws, size_t ws_size,
                              hipStream_t stream) {
    const float* q = (const float*)d_in[0];
    const float* k = (const float*)d_in[1];
    const float* v = (const float*)d_in[2];
    // d_in[3] = attention_mask: fixed pattern (first 128 tokens global) baked into the kernel.
    float* out = (float*)d_out;
    dim3 grid(NB_BLOCKS + NA_BLOCKS);  // 3264
    dim3 block(256);
    hipLaunchKernelGGL(longformer_fused, grid, block, 0, stream, q, k, v, out);
}

// Round 5
// 611.656 us; speedup vs baseline: 1.0050x; 1.0050x over previous
//
#include <hip/hip_runtime.h>
#include <hip/hip_fp16.h>
#include <math.h>

// Longformer global attention, fixed shapes: B=2,H=12,S=2048,D=64,N_GLOBAL=128.
// Output 0: context (B,H,S,D) fp32 ; Output 1: probs (B,H,S,S) fp32 (cols>=128 zero).
// Two block roles in one kernel:
//   [0,NB)     B: full 2048-key online-softmax attention for q<128 rows -> ctx
//   [NB,NB+NA) A: 128-key softmax for its 16 rows -> probs cols 0..127,
//                 zero-fill of probs cols 128..2047 for the SAME rows,
//                 and ctx = P @ V[0:128] for non-global rows (qbase>=128).
// KEY STRUCTURE (round-5 theory): every global store is issued AFTER the last
// barrier and AFTER all global loads of the block, so (a) no s_barrier ever
// drains the store queue (vmcnt(0) stall was ~5us/block in round 4), and
// (b) no load waits behind stores in the vmcnt FIFO. Waves retire into a
// background write drain -> write stream stays fed by block turnover.
// p_lds is per-warp ([w] indexed) -> no barrier needed around it at all.

namespace {
constexpr int BATCH = 2;
constexpr int HEADS = 12;
constexpr int SEQ   = 2048;
constexpr int DIM   = 64;
constexpr int NG    = 128;
constexpr int BHN   = BATCH * HEADS;                        // 24
constexpr long long CTX_SIZE = (long long)BHN * SEQ * DIM;  // 3,145,728
constexpr float SCALE = 0.125f;                             // 1/sqrt(64)

constexpr int NB_BLOCKS = (BHN * NG) / 16;                  // 192
constexpr int NA_BLOCKS = (BHN * SEQ) / 16;                 // 3072
constexpr int TAIL_F4   = (SEQ - NG) / 4;                   // 480 float4 per row tail
constexpr int TAIL_PER_THREAD = 16 * TAIL_F4 / 256;         // 30 float4 per thread
}

typedef float nfloat4 __attribute__((ext_vector_type(4)));

__device__ __forceinline__ float wave_max64(float x) {
#pragma unroll
    for (int off = 32; off > 0; off >>= 1) x = fmaxf(x, __shfl_xor(x, off));
    return x;
}
__device__ __forceinline__ float wave_sum64(float x) {
#pragma unroll
    for (int off = 32; off > 0; off >>= 1) x += __shfl_xor(x, off);
    return x;
}

__global__ __launch_bounds__(256) void longformer_fused(
    const float* __restrict__ q, const float* __restrict__ k,
    const float* __restrict__ v, float* __restrict__ out)
{
    __shared__ float  k_lds[128][68];    // 34816 B, pitch 17 f4 -> conflict-free b128 reads
    __shared__ __half p_lds[4][4][128];  //  4096 B (per-warp: no barriers around it)

    const int blk = blockIdx.x;
    float* const ctx_out   = out;
    float* const probs_out = out + CTX_SIZE;

    const int w    = threadIdx.x >> 6;
    const int lane = threadIdx.x & 63;
    const int gq   = lane >> 4;   // 0..3
    const int dq   = lane & 15;   // 0..15

    if (blk >= NB_BLOCKS) {
        // ---- A: 128-key global softmax + own-row tail zeroing ----
        const int ablk  = blk - NB_BLOCKS;
        const int bh    = ablk >> 7;          // 128 consecutive blocks share (b,h)
        const int qbase = (ablk & 127) << 4;  // 16 rows per block
        const int row0  = qbase + w * 4;
        const float* const qb = q + (size_t)bh * SEQ * DIM;
        const float* const kb = k + (size_t)bh * SEQ * DIM;   // global keys = rows 0..127
        const float* const vb = v + (size_t)bh * SEQ * DIM;

        // stage k[0:128][0:64] -> LDS (coalesced). Only loads outstanding at barrier.
#pragma unroll
        for (int j = 0; j < 8; ++j) {
            int f  = threadIdx.x + j * 256;       // float4 index 0..2047
            int g  = f >> 4;
            int ci = (f & 15) << 2;
            float4 t = *reinterpret_cast<const float4*>(kb + g * DIM + ci);
            *reinterpret_cast<float4*>(&k_lds[g][ci]) = t;
        }
        __syncthreads();

        // scores: lane owns keys g=lane and g=lane+64
        float s0[4] = {0,0,0,0}, s1[4] = {0,0,0,0};
        const float* krow0 = &k_lds[lane][0];
        const float* krow1 = &k_lds[lane + 64][0];
#pragma unroll 4
        for (int i = 0; i < 16; ++i) {
            const float4 ka = *reinterpret_cast<const float4*>(krow0 + 4 * i);
            const float4 kc = *reinterpret_cast<const float4*>(krow1 + 4 * i);
#pragma unroll
            for (int r = 0; r < 4; ++r) {
                const float4 qv = *reinterpret_cast<const float4*>(qb + (size_t)(row0 + r) * DIM + 4 * i);
                s0[r] += qv.x * ka.x + qv.y * ka.y + qv.z * ka.z + qv.w * ka.w;
                s1[r] += qv.x * kc.x + qv.y * kc.y + qv.z * kc.z + qv.w * kc.w;
            }
        }
        // softmax: probs kept in regs for the final store; fp16 copy in p_lds for PV broadcast
        float e0v[4], e1v[4];
#pragma unroll
        for (int r = 0; r < 4; ++r) {
            float a = s0[r] * SCALE, b = s1[r] * SCALE;
            float m = wave_max64(fmaxf(a, b));
            float e0 = __expf(a - m), e1 = __expf(b - m);
            float inv = 1.f / wave_sum64(e0 + e1);
            e0 *= inv; e1 *= inv;
            e0v[r] = e0; e1v[r] = e1;
            p_lds[w][r][lane]      = __float2half(e0);
            p_lds[w][r][lane + 64] = __float2half(e1);
        }

        // PV (global v loads) BEFORE any global store
        float4 c[4];
        const bool do_ctx = (qbase >= NG);
        if (do_ctx) {
#pragma unroll
            for (int r = 0; r < 4; ++r) c[r] = make_float4(0.f, 0.f, 0.f, 0.f);
#pragma unroll 2
            for (int i = 0; i < 32; ++i) {
                const int g = 4 * i + gq;
                const float4 vv = *reinterpret_cast<const float4*>(vb + g * DIM + 4 * dq);
#pragma unroll
                for (int r = 0; r < 4; ++r) {
                    const float pr = __half2float(p_lds[w][r][g]);
                    c[r].x += pr * vv.x; c[r].y += pr * vv.y;
                    c[r].z += pr * vv.z; c[r].w += pr * vv.w;
                }
            }
        }

        // ---- all global stores last; no barrier after -> background drain ----
#pragma unroll
        for (int r = 0; r < 4; ++r) {
            float* prow = probs_out + (size_t)(bh * SEQ + row0 + r) * SEQ;
            __builtin_nontemporal_store(e0v[r], prow + lane);
            __builtin_nontemporal_store(e1v[r], prow + lane + 64);
        }
        if (do_ctx) {
#pragma unroll
            for (int r = 0; r < 4; ++r) {
                c[r].x += __shfl_xor(c[r].x, 16); c[r].y += __shfl_xor(c[r].y, 16);
                c[r].z += __shfl_xor(c[r].z, 16); c[r].w += __shfl_xor(c[r].w, 16);
                c[r].x += __shfl_xor(c[r].x, 32); c[r].y += __shfl_xor(c[r].y, 32);
                c[r].z += __shfl_xor(c[r].z, 32); c[r].w += __shfl_xor(c[r].w, 32);
                if (lane < 16) {
                    nfloat4 cv; cv.x = c[r].x; cv.y = c[r].y; cv.z = c[r].z; cv.w = c[r].w;
                    nfloat4* crow = reinterpret_cast<nfloat4*>(ctx_out + (size_t)(bh * SEQ + row0 + r) * DIM + 4 * dq);
                    __builtin_nontemporal_store(cv, crow);
                }
            }
        }
        {
            float* const tail_base = probs_out + ((size_t)bh * SEQ + qbase) * SEQ;
            const nfloat4 z = (nfloat4)(0.f);
#pragma unroll
            for (int s = 0; s < TAIL_PER_THREAD; ++s) {
                int idx  = s * 256 + threadIdx.x;       // 0..7679
                int row  = idx / TAIL_F4;               // 0..15
                int c4   = idx - row * TAIL_F4;         // 0..479
                nfloat4* p = reinterpret_cast<nfloat4*>(tail_base + (size_t)row * SEQ + NG + 4 * c4);
                __builtin_nontemporal_store(z, p);
            }
        }
        return;
    }

    // ---- B: full 2048-key attention for global queries (q<128) ----
    {
        const int bh    = blk >> 3;          // 8 blocks per (b,h)
        const int qbase = (blk & 7) << 4;
        const int row0  = qbase + w * 4;
        const float* const qb = q + (size_t)bh * SEQ * DIM;
        const float* const kb = k + (size_t)bh * SEQ * DIM;
        const float* const vb = v + (size_t)bh * SEQ * DIM;

        float m[4], l[4];
        float4 c[4];
#pragma unroll
        for (int r = 0; r < 4; ++r) { m[r] = -INFINITY; l[r] = 0.f; c[r] = make_float4(0.f,0.f,0.f,0.f); }

        for (int t = 0; t < 16; ++t) {
            const float* kt = kb + (size_t)t * 128 * DIM;
            const float* vt = vb + (size_t)t * 128 * DIM;

            __syncthreads();  // protect k_lds from previous tile's score-phase readers
#pragma unroll
            for (int j = 0; j < 8; ++j) {
                int f  = threadIdx.x + j * 256;
                int g  = f >> 4;
                int ci = (f & 15) << 2;
                float4 tt = *reinterpret_cast<const float4*>(kt + g * DIM + ci);
                *reinterpret_cast<float4*>(&k_lds[g][ci]) = tt;
            }
            __syncthreads();

            float s0[4] = {0,0,0,0}, s1[4] = {0,0,0,0};
            const float* krow0 = &k_lds[lane][0];
            const float* krow1 = &k_lds[lane + 64][0];
#pragma unroll 4
            for (int i = 0; i < 16; ++i) {
                const float4 ka = *reinterpret_cast<const float4*>(krow0 + 4 * i);
                const float4 kc = *reinterpret_cast<const float4*>(krow1 + 4 * i);
#pragma unroll
                for (int r = 0; r < 4; ++r) {
                    const float4 qv = *reinterpret_cast<const float4*>(qb + (size_t)(row0 + r) * DIM + 4 * i);
                    s0[r] += qv.x * ka.x + qv.y * ka.y + qv.z * ka.z + qv.w * ka.w;
                    s1[r] += qv.x * kc.x + qv.y * kc.y + qv.z * kc.z + qv.w * kc.w;
                }
            }
#pragma unroll
            for (int r = 0; r < 4; ++r) {
                float a  = s0[r] * SCALE, b = s1[r] * SCALE;
                float tm = wave_max64(fmaxf(a, b));
                float mn = fmaxf(m[r], tm);
                float corr = __expf(m[r] - mn);       // exp(-inf)=0 on first tile
                float e0 = __expf(a - mn), e1 = __expf(b - mn);
                float ts = wave_sum64(e0 + e1);
                l[r] = l[r] * corr + ts;
                c[r].x *= corr; c[r].y *= corr; c[r].z *= corr; c[r].w *= corr;
                m[r] = mn;
                p_lds[w][r][lane]      = __float2half(e0);
                p_lds[w][r][lane + 64] = __float2half(e1);
            }
            // no barrier: p_lds[w] is warp-local; lgkmcnt ordering suffices
#pragma unroll 2
            for (int i = 0; i < 32; ++i) {
                const int g = 4 * i + gq;
                const float4 vv = *reinterpret_cast<const float4*>(vt + g * DIM + 4 * dq);
#pragma unroll
                for (int r = 0; r < 4; ++r) {
                    const float pr = __half2float(p_lds[w][r][g]);
                    c[r].x += pr * vv.x; c[r].y += pr * vv.y;
                    c[r].z += pr * vv.z; c[r].w += pr * vv.w;
                }
            }
        }
#pragma unroll
        for (int r = 0; r < 4; ++r) {
            c[r].x += __shfl_xor(c[r].x, 16); c[r].y += __shfl_xor(c[r].y, 16);
            c[r].z += __shfl_xor(c[r].z, 16); c[r].w += __shfl_xor(c[r].w, 16);
            c[r].x += __shfl_xor(c[r].x, 32); c[r].y += __shfl_xor(c[r].y, 32);
            c[r].z += __shfl_xor(c[r].z, 32); c[r].w += __shfl_xor(c[r].w, 32);
            const float inv = 1.f / l[r];
            c[r].x *= inv; c[r].y *= inv; c[r].z *= inv; c[r].w *= inv;
            if (lane < 16) {
                nfloat4 cv; cv.x = c[r].x; cv.y = c[r].y; cv.z = c[r].z; cv.w = c[r].w;
                nfloat4* crow = reinterpret_cast<nfloat4*>(ctx_out + (size_t)(bh * SEQ + row0 + r) * DIM + 4 * dq);
                __builtin_nontemporal_store(cv, crow);
            }
        }
    }
}

extern "C" void kernel_launch(void* const* d_in, const int* in_sizes, int n_in,
                              void* d_out, int out_size, void* d_ws, size_t ws_size,
                              hipStream_t stream) {
    const float* q = (const float*)d_in[0];
    const float* k = (const float*)d_in[1];
    const float* v = (const float*)d_in[2];
    // d_in[3] = attention_mask: fixed pattern (first 128 tokens global) baked into the kernel.
    float* out = (float*)d_out;
    dim3 grid(NB_BLOCKS + NA_BLOCKS);  // 3264
    dim3 block(256);
    hipLaunchKernelGGL(longformer_fused, grid, block, 0, stream, q, k, v, out);
}